// Round 10
// baseline (235.961 us; speedup 1.0000x reference)
//
#include <hip/hip_runtime.h>
#include <hip/hip_cooperative_groups.h>
#include <hip/hip_bf16.h>
#include <stdint.h>

// ScaledDotProductAttention S=4096 D=1024 fp32.
// R10: cooperative single-kernel (grid 512 = 2 blk/CU, static balanced split, 4
// grid.syncs) with occupancy guard + R8's proven 5-launch path as compiled fallback.
// R9's grid-1024 cooperative launch was rejected (output all-zeros = launch error):
// 64 VGPR + 64 AGPR = exactly 128 unified regs leaves zero allocator slack for 4
// blk/CU. 512 blocks has 2x margin on regs and LDS. Work maps balanced: bids i,i+256
// share a CU -> G1 768 tiles = 3/CU, G2/G3 1024 tiles = 4/CU, same per-CU work as R8
// minus ~37us of launch boundaries. GEMM core unchanged from R8 (BN=128 BK=64,
// XOR bank swizzle conflicts=0, global_load_lds w=16, mfma 16x16x32 bf16).

typedef __bf16 bf16_t;
typedef __bf16 bf16x4 __attribute__((ext_vector_type(4)));
typedef __bf16 bf16x8 __attribute__((ext_vector_type(8)));
typedef float f32x4 __attribute__((ext_vector_type(4)));

namespace cg = cooperative_groups;

#define AS1 __attribute__((address_space(1)))
#define AS3 __attribute__((address_space(3)))

__device__ __forceinline__ void async_ld16(const void* g, void* l) {
  // global -> LDS DMA, 16B/lane; LDS dest is wave-uniform base + lane*16 by HW rule.
  __builtin_amdgcn_global_load_lds((AS1 void*)g, (AS3 void*)l, 16, 0, 0);
}

// BN=128, BK=64 GEMM tile, 4 waves, mfma_f32_16x16x32_bf16, global_load_lds w=16.
// MODE 0: QKV epilogue (bias; Q scaled 1/32; V transposed).
// MODE 1: S epilogue: store exp(acc) bf16 ldc=4096, atomicAdd fp32 row sums.
// MODE 2: O epilogue: zz<3 -> bf16 partial to o_zz; zz==3 -> fp32 to fout (1/rowsum).
template <int MODE>
__device__ void gemm_core(bf16_t* As, bf16_t* Bs, const int t, const int m0,
                          const int n0, const int k0, const int zz,
                          const bf16_t* __restrict__ A,
                          const bf16_t* __restrict__ B, const int ld,
                          const int Klen, bf16_t* __restrict__ o0,
                          bf16_t* __restrict__ o1, bf16_t* __restrict__ o2,
                          const float* __restrict__ b0,
                          const float* __restrict__ b1,
                          const float* __restrict__ b2,
                          float* __restrict__ fout,
                          float* __restrict__ rowsum) {
  constexpr int BN = 128, BK = 64;
  constexpr int NF = BN / 32;   // n-frags per wave
  constexpr int KS = BK / 32;   // mfma k-steps per tile
  constexpr int CH = BK / 8;    // 16B chunks per LDS row
  constexpr int RS = 256 / CH;  // rows staged per DMA round

  const int lane = t & 63;
  const int wave = t >> 6;
  const int wm = wave >> 1;
  const int wn = wave & 1;
  const int q = lane >> 4;
  const int l16 = lane & 15;
  const int wnoff = wn * (BN / 2);

  const f32x4 zero4 = {0.f, 0.f, 0.f, 0.f};
  f32x4 acc[4][NF];
#pragma unroll
  for (int i = 0; i < 4; ++i)
#pragma unroll
    for (int j = 0; j < NF; ++j) acc[i][j] = zero4;

  // Staging swizzle (R5-proven, conflict-free): GLOBAL chunk = slot ^ (srow&7);
  // read side inverts with xf = l16&7 (per-lane constant on rows 16a+l16).
  const int srow = t / CH;
  const int schunk = (t % CH) ^ (srow & 7);
  const bf16_t* Ab = A + (size_t)(m0 + srow) * ld + k0 + schunk * 8;
  const bf16_t* Bb = B + (size_t)(n0 + srow) * ld + k0 + schunk * 8;
  bf16_t* Asl = As + t * 8;
  bf16_t* Bsl = Bs + t * 8;

  const int xf = l16 & 7;
  const int ar = wm * 64 + l16;
  const int br = wnoff + l16;

  for (int kt = 0; kt < Klen; kt += BK) {
#pragma unroll
    for (int rr = 0; rr < 128 / RS; ++rr)
      async_ld16(Ab + kt + (size_t)(rr * RS) * ld, Asl + rr * RS * BK);
#pragma unroll
    for (int rr = 0; rr < BN / RS; ++rr)
      async_ld16(Bb + kt + (size_t)(rr * RS) * ld, Bsl + rr * RS * BK);
    __syncthreads();

#pragma unroll
    for (int s = 0; s < KS; ++s) {
      bf16x8 fa[4], fb[NF];
#pragma unroll
      for (int im = 0; im < 4; ++im)
        fa[im] = *(const bf16x8*)(As + (ar + im * 16) * BK +
                                  (((s * 4 + q) ^ xf) * 8));
#pragma unroll
      for (int j = 0; j < NF; ++j)
        fb[j] = *(const bf16x8*)(Bs + (br + j * 16) * BK +
                                 (((s * 4 + q) ^ xf) * 8));
#pragma unroll
      for (int im = 0; im < 4; ++im)
#pragma unroll
        for (int j = 0; j < NF; ++j)
          acc[im][j] = __builtin_amdgcn_mfma_f32_16x16x32_bf16(
              fa[im], fb[j], acc[im][j], 0, 0, 0);
    }
    __syncthreads();
  }

  // C/D layout: col = lane&15, row = quad*4 + reg (m89/m91-verified).
  const int mBase = m0 + wm * 64 + q * 4;

  if constexpr (MODE == 0) {
    const int sel = n0 >> 10;  // 0=Q 1=K 2=V
    const int nl0 = (n0 & 1023) + wnoff + l16;
    const float* bias = (sel == 0) ? b0 : ((sel == 1) ? b1 : b2);
    const float sc = (sel == 0) ? 0.03125f : 1.0f;  // 1/sqrt(1024) folded into Q
#pragma unroll
    for (int j = 0; j < NF; ++j) {
      const int nl = nl0 + j * 16;
      const float bb = bias[nl];
#pragma unroll
      for (int im = 0; im < 4; ++im) {
        const int mr = mBase + im * 16;
        if (sel < 2) {
          bf16_t* dst = (sel == 0) ? o0 : o1;
#pragma unroll
          for (int r = 0; r < 4; ++r)
            dst[(size_t)(mr + r) * 1024 + nl] =
                (bf16_t)((acc[im][j][r] + bb) * sc);
        } else {
          bf16x4 v;  // V^T[d][key]: 4 regs = 4 consecutive keys -> packed 8B store
#pragma unroll
          for (int r = 0; r < 4; ++r) v[r] = (bf16_t)(acc[im][j][r] + bb);
          *(bf16x4*)(o2 + (size_t)nl * 4096 + mr) = v;
        }
      }
    }
  } else if constexpr (MODE == 1) {
    float ps[4][4];
#pragma unroll
    for (int im = 0; im < 4; ++im)
#pragma unroll
      for (int r = 0; r < 4; ++r) ps[im][r] = 0.f;
#pragma unroll
    for (int j = 0; j < NF; ++j) {
      const int n = n0 + wnoff + j * 16 + l16;
#pragma unroll
      for (int im = 0; im < 4; ++im) {
        const int mr = mBase + im * 16;
#pragma unroll
        for (int r = 0; r < 4; ++r) {
          const float e = __expf(acc[im][j][r]);
          ps[im][r] += e;
          o0[(size_t)(mr + r) * 4096 + n] = (bf16_t)e;
        }
      }
    }
#pragma unroll
    for (int im = 0; im < 4; ++im)
#pragma unroll
      for (int r = 0; r < 4; ++r) {
        float v = ps[im][r];
        v += __shfl_xor(v, 1);
        v += __shfl_xor(v, 2);
        v += __shfl_xor(v, 4);
        v += __shfl_xor(v, 8);
        ps[im][r] = v;
      }
    if (l16 == 0) {
#pragma unroll
      for (int im = 0; im < 4; ++im)
#pragma unroll
        for (int r = 0; r < 4; ++r)
          atomicAdd(rowsum + mBase + im * 16 + r, ps[im][r]);
    }
  } else {
    float inv[4][4];
#pragma unroll
    for (int im = 0; im < 4; ++im)
#pragma unroll
      for (int r = 0; r < 4; ++r)
        inv[im][r] = 1.0f / rowsum[mBase + im * 16 + r];
    if (zz < 3) {  // bf16 partial (normalized); partials over splits sum to O
      bf16_t* pp = (zz == 0) ? o0 : ((zz == 1) ? o1 : o2);
#pragma unroll
      for (int im = 0; im < 4; ++im) {
        const int mr = mBase + im * 16;
#pragma unroll
        for (int j = 0; j < NF; ++j) {
          const int n = n0 + wnoff + j * 16 + l16;
#pragma unroll
          for (int r = 0; r < 4; ++r)
            pp[(size_t)(mr + r) * 1024 + n] =
                (bf16_t)(acc[im][j][r] * inv[im][r]);
        }
      }
    } else {  // zz==3: fp32 partial straight into d_out; reduce adds the rest
#pragma unroll
      for (int im = 0; im < 4; ++im) {
        const int mr = mBase + im * 16;
#pragma unroll
        for (int j = 0; j < NF; ++j) {
          const int n = n0 + wnoff + j * 16 + l16;
#pragma unroll
          for (int r = 0; r < 4; ++r)
            fout[(size_t)(mr + r) * 1024 + n] = acc[im][j][r] * inv[im][r];
        }
      }
    }
  }
}

// ---------------- cooperative fused kernel (grid 512, 2 blk/CU) ----------------
__global__ __launch_bounds__(256, 2) void fused_attn(
    const float* __restrict__ X, const float* __restrict__ Wq,
    const float* __restrict__ bq, const float* __restrict__ Wk,
    const float* __restrict__ bk, const float* __restrict__ Wv,
    const float* __restrict__ bv, float* __restrict__ out,
    bf16_t* __restrict__ Xb, bf16_t* __restrict__ Wb,
    bf16_t* __restrict__ Qb, bf16_t* __restrict__ Kb,
    bf16_t* __restrict__ Vt, bf16_t* __restrict__ Sc,
    float* __restrict__ rowsum) {
  __shared__ bf16_t As[128 * 64];
  __shared__ bf16_t Bs[128 * 64];
  cg::grid_group grid = cg::this_grid();
  const int bid = blockIdx.x;
  const int t = threadIdx.x;

  // ---- phase 0: convert X|Wq|Wk|Wv to bf16; zero rowsum ----
  for (int u = bid; u < 7184; u += 512) {
    const int i = u * 256 + t;  // float4 index
    if (i >= 1835008) {
      rowsum[i - 1835008] = 0.f;  // tail: 16 units x 256 = 4096 floats
    } else {
      const float* src;
      bf16_t* dst;
      int off;
      if (i < 1048576) {
        src = X; dst = Xb; off = i;
      } else {
        const int w = i - 1048576;
        const int sel = w >> 18;
        off = w & 0x3FFFF;
        src = (sel == 0) ? Wq : ((sel == 1) ? Wk : Wv);
        dst = Wb + (size_t)sel * (1024 * 1024);
      }
      const float4 v = ((const float4*)src)[off];
      bf16x4 o;
      o[0] = (bf16_t)v.x; o[1] = (bf16_t)v.y;
      o[2] = (bf16_t)v.z; o[3] = (bf16_t)v.w;
      ((bf16x4*)dst)[off] = o;
    }
  }
  grid.sync();

  // ---- phase 1: G1 QKV = Xb @ Wb^T + bias (768 tiles; bids i,i+256 share a CU
  //      so the 2-tiles-for-bid<256 split lands 3 tiles per CU uniformly) ----
  for (int v = bid; v < 768; v += 512) {
    const int n0 = (v % 24) * 128;
    const int m0 = (v / 24) * 128;
    gemm_core<0>(As, Bs, t, m0, n0, 0, 0, Xb, Wb, 1024, 1024, Qb, Kb, Vt, bq,
                 bk, bv, nullptr, nullptr);
  }
  grid.sync();

  // ---- phase 2: G2 Sc = exp(Qb @ Kb^T) + rowsum atomics (XCD swizzle) ----
  for (int v = bid; v < 1024; v += 512) {
    const int xcd = v & 7, sl = v >> 3;
    const int m0 = ((xcd >> 2) * 16 + (sl >> 3)) * 128;
    const int n0 = ((xcd & 3) * 8 + (sl & 7)) * 128;
    gemm_core<1>(As, Bs, t, m0, n0, 0, 0, Qb, Kb, 1024, 1024, Sc, nullptr,
                 nullptr, nullptr, nullptr, nullptr, nullptr, rowsum);
  }
  grid.sync();

  // ---- phase 3: G3 O-partials, split-K=4, XCD-partitioned decode ----
  for (int v = bid; v < 1024; v += 512) {
    const int xcd = v & 7, s = v >> 3;
    const int zz = xcd >> 1;
    const int mt = (xcd & 1) * 16 + (s >> 3);
    const int nt = s & 7;
    gemm_core<2>(As, Bs, t, mt * 128, nt * 128, zz * 1024, zz, Sc, Vt, 4096,
                 1024, Xb, Qb, Kb, nullptr, nullptr, nullptr, out, rowsum);
  }
  grid.sync();

  // ---- phase 4: out += p0 + p1 + p2 ----
  for (int u = bid; u < 2048; u += 512) {
    const int i = u * 256 + t;  // bf16x8 index
    const bf16x8 a = ((const bf16x8*)Xb)[i];
    const bf16x8 b = ((const bf16x8*)Qb)[i];
    const bf16x8 c = ((const bf16x8*)Kb)[i];
    float4 lo = ((const float4*)out)[2 * i];
    float4 hi = ((const float4*)out)[2 * i + 1];
    lo.x += (float)a[0] + (float)b[0] + (float)c[0];
    lo.y += (float)a[1] + (float)b[1] + (float)c[1];
    lo.z += (float)a[2] + (float)b[2] + (float)c[2];
    lo.w += (float)a[3] + (float)b[3] + (float)c[3];
    hi.x += (float)a[4] + (float)b[4] + (float)c[4];
    hi.y += (float)a[5] + (float)b[5] + (float)c[5];
    hi.z += (float)a[6] + (float)b[6] + (float)c[6];
    hi.w += (float)a[7] + (float)b[7] + (float)c[7];
    ((float4*)out)[2 * i] = lo;
    ((float4*)out)[2 * i + 1] = hi;
  }
}

// ---------------- R8 fallback path (proven 206.9 us) ----------------
template <int MODE>
__global__ __launch_bounds__(256, 2) void gemm_sep(
    const bf16_t* __restrict__ A, const bf16_t* __restrict__ B, const int ld,
    const int Klen,
    bf16_t* __restrict__ o0, bf16_t* __restrict__ o1, bf16_t* __restrict__ o2,
    const float* __restrict__ b0, const float* __restrict__ b1,
    const float* __restrict__ b2, float* __restrict__ fout,
    float* __restrict__ rowsum) {
  __shared__ bf16_t As[128 * 64];
  __shared__ bf16_t Bs[128 * 64];
  int m0, n0, k0 = 0, zz = 0;
  if constexpr (MODE == 1) {
    const int bid = blockIdx.y * 32 + blockIdx.x;
    const int xcd = bid & 7, sl = bid >> 3;
    m0 = ((xcd >> 2) * 16 + (sl >> 3)) * 128;
    n0 = ((xcd & 3) * 8 + (sl & 7)) * 128;
  } else if constexpr (MODE == 2) {
    const int lin = blockIdx.x;
    const int xcd = lin & 7, s = lin >> 3;
    zz = xcd >> 1;
    m0 = ((xcd & 1) * 16 + (s >> 3)) * 128;
    n0 = (s & 7) * 128;
    k0 = zz * Klen;
  } else {
    n0 = blockIdx.x * 128;
    m0 = blockIdx.y * 128;
  }
  gemm_core<MODE>(As, Bs, threadIdx.x, m0, n0, k0, zz, A, B, ld, Klen, o0, o1,
                  o2, b0, b1, b2, fout, rowsum);
}

__global__ __launch_bounds__(256) void cvt_all(
    const float* __restrict__ X, const float* __restrict__ Wq,
    const float* __restrict__ Wk, const float* __restrict__ Wv,
    bf16_t* __restrict__ Xb, bf16_t* __restrict__ Wb,
    float* __restrict__ rowsum) {
  int i = blockIdx.x * 256 + threadIdx.x;
  if (i >= 1835008) {
    rowsum[i - 1835008] = 0.f;
    return;
  }
  const float* src;
  bf16_t* dst;
  int off;
  if (i < 1048576) {
    src = X; dst = Xb; off = i;
  } else {
    const int w = i - 1048576;
    const int sel = w >> 18;
    off = w & 0x3FFFF;
    src = (sel == 0) ? Wq : ((sel == 1) ? Wk : Wv);
    dst = Wb + (size_t)sel * (1024 * 1024);
  }
  const float4 v = ((const float4*)src)[off];
  bf16x4 o;
  o[0] = (bf16_t)v.x; o[1] = (bf16_t)v.y; o[2] = (bf16_t)v.z; o[3] = (bf16_t)v.w;
  ((bf16x4*)dst)[off] = o;
}

__global__ __launch_bounds__(256) void reduce_out(
    const bf16_t* __restrict__ p0, const bf16_t* __restrict__ p1,
    const bf16_t* __restrict__ p2, float* __restrict__ out) {
  const int i = blockIdx.x * 256 + threadIdx.x;
  const bf16x8 a = ((const bf16x8*)p0)[i];
  const bf16x8 b = ((const bf16x8*)p1)[i];
  const bf16x8 c = ((const bf16x8*)p2)[i];
  float4 lo = ((const float4*)out)[2 * i];
  float4 hi = ((const float4*)out)[2 * i + 1];
  lo.x += (float)a[0] + (float)b[0] + (float)c[0];
  lo.y += (float)a[1] + (float)b[1] + (float)c[1];
  lo.z += (float)a[2] + (float)b[2] + (float)c[2];
  lo.w += (float)a[3] + (float)b[3] + (float)c[3];
  hi.x += (float)a[4] + (float)b[4] + (float)c[4];
  hi.y += (float)a[5] + (float)b[5] + (float)c[5];
  hi.z += (float)a[6] + (float)b[6] + (float)c[6];
  hi.w += (float)a[7] + (float)b[7] + (float)c[7];
  ((float4*)out)[2 * i] = lo;
  ((float4*)out)[2 * i + 1] = hi;
}

extern "C" void kernel_launch(void* const* d_in, const int* in_sizes, int n_in,
                              void* d_out, int out_size, void* d_ws,
                              size_t ws_size, hipStream_t stream) {
  const int S = 4096, D = 1024;
  const float* X  = (const float*)d_in[0];
  const float* Wq = (const float*)d_in[1];
  const float* bq = (const float*)d_in[2];
  const float* Wk = (const float*)d_in[3];
  const float* bk = (const float*)d_in[4];
  const float* Wv = (const float*)d_in[5];
  const float* bv = (const float*)d_in[6];
  float* out = (float*)d_out;

  bf16_t* Xb = (bf16_t*)d_ws;            // [4096][1024]
  bf16_t* Wb = Xb + (size_t)S * D;       // [3072][1024]
  bf16_t* Qb = Wb + (size_t)3 * D * D;   // [4096][1024], pre-scaled by 1/32
  bf16_t* Kb = Qb + (size_t)S * D;       // [4096][1024]
  bf16_t* Vt = Kb + (size_t)S * D;       // [1024][4096]  V transposed
  bf16_t* Sc = Vt + (size_t)D * S;       // [4096][4096]  exp(scores)
  float* rowsum = (float*)(Sc + (size_t)S * S);  // [4096]

  // Occupancy guard (pure query: graph-capture-safe, deterministic each call).
  int occ = 0;
  hipError_t qerr =
      hipOccupancyMaxActiveBlocksPerMultiprocessor(&occ, fused_attn, 256, 0);
  const bool useCoop = (qerr == hipSuccess) && (occ >= 2);

  if (useCoop) {
    void* args[] = {&X, &Wq, &bq, &Wk, &bk, &Wv, &bv, &out,
                    &Xb, &Wb, &Qb, &Kb, &Vt, &Sc, &rowsum};
    hipLaunchCooperativeKernel(reinterpret_cast<void*>(fused_attn), dim3(512),
                               dim3(256), args, 0, stream);
  } else {
    // R8 path: 5 launches, proven 206.9 us.
    cvt_all<<<7184, 256, 0, stream>>>(X, Wq, Wk, Wv, Xb, Wb, rowsum);
    gemm_sep<0><<<dim3(24, 32), 256, 0, stream>>>(
        Xb, Wb, D, D, Qb, Kb, Vt, bq, bk, bv, nullptr, nullptr);
    gemm_sep<1><<<dim3(32, 32), 256, 0, stream>>>(
        Qb, Kb, D, D, Sc, nullptr, nullptr, nullptr, nullptr, nullptr, nullptr,
        rowsum);
    gemm_sep<2><<<1024, 256, 0, stream>>>(
        Sc, Vt, S, S / 4, Xb, Qb, Kb, nullptr, nullptr, nullptr, out, rowsum);
    reduce_out<<<S * D / 8 / 256, 256, 0, stream>>>(Xb, Qb, Kb, out);
  }
}

// Round 11
// 203.868 us; speedup vs baseline: 1.1574x; 1.1574x over previous
//
#include <hip/hip_runtime.h>
#include <hip/hip_bf16.h>
#include <stdint.h>

// ScaledDotProductAttention S=4096 D=1024 fp32.
// R11 = R8 (proven 206.9us: cvt | G1 QKV | G2 exp(QK^T)+rowsum | G3 split-K=4 XCD |
// reduce) + G1's V^T epilogue routed through LDS. R8's 8B-scatter V^T stores (lane
// stride 8KB) defeated write-combining -> fetch-for-write RMW (G1 WRITE 40MB vs 24
// ideal). Now: acc -> LDS tile (stride 136, 2-way banks = free) -> coalesced bf16x8
// stores (256B runs). Cooperative fusion abandoned: R10 measured 2 blk/CU ceiling
// (188 unified regs) makes fused phases strictly slower than separate launches.

typedef __bf16 bf16_t;
typedef __bf16 bf16x4 __attribute__((ext_vector_type(4)));
typedef __bf16 bf16x8 __attribute__((ext_vector_type(8)));
typedef float f32x4 __attribute__((ext_vector_type(4)));

#define AS1 __attribute__((address_space(1)))
#define AS3 __attribute__((address_space(3)))

__device__ __forceinline__ void async_ld16(const void* g, void* l) {
  // global -> LDS DMA, 16B/lane; LDS dest is wave-uniform base + lane*16 by HW rule.
  __builtin_amdgcn_global_load_lds((AS1 void*)g, (AS3 void*)l, 16, 0, 0);
}

// BN=128, BK=64 GEMM tile, 4 waves, mfma_f32_16x16x32_bf16, global_load_lds w=16.
// As/Bs must be ONE contiguous 32KB LDS block (As first): the MODE-0 V^T epilogue
// reuses 17.4KB of it as a transpose staging tile after the K-loop.
// MODE 0: QKV epilogue (bias; Q scaled 1/32; V transposed via LDS).
// MODE 1: S epilogue: store exp(acc) bf16 ldc=4096, atomicAdd fp32 row sums.
// MODE 2: O epilogue: zz<3 -> bf16 partial to o_zz; zz==3 -> fp32 to fout (1/rowsum).
template <int MODE>
__device__ void gemm_core(bf16_t* As, bf16_t* Bs, const int t, const int m0,
                          const int n0, const int k0, const int zz,
                          const bf16_t* __restrict__ A,
                          const bf16_t* __restrict__ B, const int ld,
                          const int Klen, bf16_t* __restrict__ o0,
                          bf16_t* __restrict__ o1, bf16_t* __restrict__ o2,
                          const float* __restrict__ b0,
                          const float* __restrict__ b1,
                          const float* __restrict__ b2,
                          float* __restrict__ fout,
                          float* __restrict__ rowsum) {
  constexpr int BN = 128, BK = 64;
  constexpr int NF = BN / 32;   // n-frags per wave
  constexpr int KS = BK / 32;   // mfma k-steps per tile
  constexpr int CH = BK / 8;    // 16B chunks per LDS row
  constexpr int RS = 256 / CH;  // rows staged per DMA round

  const int lane = t & 63;
  const int wave = t >> 6;
  const int wm = wave >> 1;
  const int wn = wave & 1;
  const int q = lane >> 4;
  const int l16 = lane & 15;
  const int wnoff = wn * (BN / 2);

  const f32x4 zero4 = {0.f, 0.f, 0.f, 0.f};
  f32x4 acc[4][NF];
#pragma unroll
  for (int i = 0; i < 4; ++i)
#pragma unroll
    for (int j = 0; j < NF; ++j) acc[i][j] = zero4;

  // Staging swizzle (R5-proven, conflict-free): GLOBAL chunk = slot ^ (srow&7);
  // read side inverts with xf = l16&7 (per-lane constant on rows 16a+l16).
  const int srow = t / CH;
  const int schunk = (t % CH) ^ (srow & 7);
  const bf16_t* Ab = A + (size_t)(m0 + srow) * ld + k0 + schunk * 8;
  const bf16_t* Bb = B + (size_t)(n0 + srow) * ld + k0 + schunk * 8;
  bf16_t* Asl = As + t * 8;
  bf16_t* Bsl = Bs + t * 8;

  const int xf = l16 & 7;
  const int ar = wm * 64 + l16;
  const int br = wnoff + l16;

  for (int kt = 0; kt < Klen; kt += BK) {
#pragma unroll
    for (int rr = 0; rr < 128 / RS; ++rr)
      async_ld16(Ab + kt + (size_t)(rr * RS) * ld, Asl + rr * RS * BK);
#pragma unroll
    for (int rr = 0; rr < BN / RS; ++rr)
      async_ld16(Bb + kt + (size_t)(rr * RS) * ld, Bsl + rr * RS * BK);
    __syncthreads();

#pragma unroll
    for (int s = 0; s < KS; ++s) {
      bf16x8 fa[4], fb[NF];
#pragma unroll
      for (int im = 0; im < 4; ++im)
        fa[im] = *(const bf16x8*)(As + (ar + im * 16) * BK +
                                  (((s * 4 + q) ^ xf) * 8));
#pragma unroll
      for (int j = 0; j < NF; ++j)
        fb[j] = *(const bf16x8*)(Bs + (br + j * 16) * BK +
                                 (((s * 4 + q) ^ xf) * 8));
#pragma unroll
      for (int im = 0; im < 4; ++im)
#pragma unroll
        for (int j = 0; j < NF; ++j)
          acc[im][j] = __builtin_amdgcn_mfma_f32_16x16x32_bf16(
              fa[im], fb[j], acc[im][j], 0, 0, 0);
    }
    __syncthreads();
  }

  // C/D layout: col = lane&15, row = quad*4 + reg (m89/m91-verified).
  const int mBase = m0 + wm * 64 + q * 4;

  if constexpr (MODE == 0) {
    const int sel = n0 >> 10;  // 0=Q 1=K 2=V
    const int nl0 = (n0 & 1023) + wnoff + l16;
    if (sel < 2) {
      const float* bias = (sel == 0) ? b0 : b1;
      const float sc = (sel == 0) ? 0.03125f : 1.0f;  // 1/sqrt(1024) in Q
      bf16_t* dst = (sel == 0) ? o0 : o1;
#pragma unroll
      for (int j = 0; j < NF; ++j) {
        const int nl = nl0 + j * 16;
        const float bb = bias[nl];
#pragma unroll
        for (int im = 0; im < 4; ++im) {
          const int mr = mBase + im * 16;
#pragma unroll
          for (int r = 0; r < 4; ++r)
            dst[(size_t)(mr + r) * 1024 + nl] =
                (bf16_t)((acc[im][j][r] + bb) * sc);
        }
      }
    } else {
      // V^T epilogue via LDS transpose (R11). Direct 8B scatter (8KB lane
      // stride) caused RMW inflation (R8: +16MB WRITE). Two passes, one per
      // wn-half (64 d-rows x 128 keys); LDS row stride 136 elems: 16B-aligned
      // (272B), write banks (4*l16+8*im+2*q) = 2 lanes/bank-pair (free, m136);
      // drain is 16B/lane, 256B contiguous per Vt row -> full-line stores.
      bf16_t* vs = As;  // needs 64*136*2B = 17.4KB of the contiguous As+Bs 32KB
      const int dg0 = (n0 & 1023);
#pragma unroll
      for (int h = 0; h < 2; ++h) {
        if (wn == h) {
#pragma unroll
          for (int j = 0; j < NF; ++j) {
            const int dl = j * 16 + l16;  // 0..63 within this half
            const float bb = b2[dg0 + h * 64 + dl];
#pragma unroll
            for (int im = 0; im < 4; ++im) {
              bf16x4 v;
#pragma unroll
              for (int r = 0; r < 4; ++r) v[r] = (bf16_t)(acc[im][j][r] + bb);
              *(bf16x4*)(vs + dl * 136 + wm * 64 + im * 16 + q * 4) = v;
            }
          }
        }
        __syncthreads();
#pragma unroll
        for (int rr = 0; rr < 4; ++rr) {
          const int task = rr * 256 + t;
          const int row = task >> 4, ck = task & 15;
          *(bf16x8*)(o2 + (size_t)(dg0 + h * 64 + row) * 4096 + m0 + ck * 8) =
              *(const bf16x8*)(vs + row * 136 + ck * 8);
        }
        __syncthreads();
      }
    }
  } else if constexpr (MODE == 1) {
    float ps[4][4];
#pragma unroll
    for (int im = 0; im < 4; ++im)
#pragma unroll
      for (int r = 0; r < 4; ++r) ps[im][r] = 0.f;
#pragma unroll
    for (int j = 0; j < NF; ++j) {
      const int n = n0 + wnoff + j * 16 + l16;
#pragma unroll
      for (int im = 0; im < 4; ++im) {
        const int mr = mBase + im * 16;
#pragma unroll
        for (int r = 0; r < 4; ++r) {
          const float e = __expf(acc[im][j][r]);
          ps[im][r] += e;
          o0[(size_t)(mr + r) * 4096 + n] = (bf16_t)e;
        }
      }
    }
#pragma unroll
    for (int im = 0; im < 4; ++im)
#pragma unroll
      for (int r = 0; r < 4; ++r) {
        float v = ps[im][r];
        v += __shfl_xor(v, 1);
        v += __shfl_xor(v, 2);
        v += __shfl_xor(v, 4);
        v += __shfl_xor(v, 8);
        ps[im][r] = v;
      }
    if (l16 == 0) {
#pragma unroll
      for (int im = 0; im < 4; ++im)
#pragma unroll
        for (int r = 0; r < 4; ++r)
          atomicAdd(rowsum + mBase + im * 16 + r, ps[im][r]);
    }
  } else {
    float inv[4][4];
#pragma unroll
    for (int im = 0; im < 4; ++im)
#pragma unroll
      for (int r = 0; r < 4; ++r)
        inv[im][r] = 1.0f / rowsum[mBase + im * 16 + r];
    if (zz < 3) {  // bf16 partial (normalized); partials over splits sum to O
      bf16_t* pp = (zz == 0) ? o0 : ((zz == 1) ? o1 : o2);
#pragma unroll
      for (int im = 0; im < 4; ++im) {
        const int mr = mBase + im * 16;
#pragma unroll
        for (int j = 0; j < NF; ++j) {
          const int n = n0 + wnoff + j * 16 + l16;
#pragma unroll
          for (int r = 0; r < 4; ++r)
            pp[(size_t)(mr + r) * 1024 + n] =
                (bf16_t)(acc[im][j][r] * inv[im][r]);
        }
      }
    } else {  // zz==3: fp32 partial straight into d_out; reduce adds the rest
#pragma unroll
      for (int im = 0; im < 4; ++im) {
        const int mr = mBase + im * 16;
#pragma unroll
        for (int j = 0; j < NF; ++j) {
          const int n = n0 + wnoff + j * 16 + l16;
#pragma unroll
          for (int r = 0; r < 4; ++r)
            fout[(size_t)(mr + r) * 1024 + n] = acc[im][j][r] * inv[im][r];
        }
      }
    }
  }
}

template <int MODE>
__global__ __launch_bounds__(256, 2) void gemm_sep(
    const bf16_t* __restrict__ A, const bf16_t* __restrict__ B, const int ld,
    const int Klen,
    bf16_t* __restrict__ o0, bf16_t* __restrict__ o1, bf16_t* __restrict__ o2,
    const float* __restrict__ b0, const float* __restrict__ b1,
    const float* __restrict__ b2, float* __restrict__ fout,
    float* __restrict__ rowsum) {
  __shared__ bf16_t smem[2 * 128 * 64];  // contiguous As|Bs (32KB)
  bf16_t* As = smem;
  bf16_t* Bs = smem + 128 * 64;
  int m0, n0, k0 = 0, zz = 0;
  if constexpr (MODE == 1) {
    // XCD-aware swizzle (grid 32x32): xcd owns a 16m x 8n region (bijective).
    const int bid = blockIdx.y * 32 + blockIdx.x;
    const int xcd = bid & 7, sl = bid >> 3;
    m0 = ((xcd >> 2) * 16 + (sl >> 3)) * 128;
    n0 = ((xcd & 3) * 8 + (sl & 7)) * 128;
  } else if constexpr (MODE == 2) {
    // XCD partition (1D grid 1024): each XCD owns (z, m-half) = 128 tiles,
    // L2 footprint A 4MB + B 2MB (R7-verified: FETCH 135 -> 50 MB).
    const int lin = blockIdx.x;
    const int xcd = lin & 7, s = lin >> 3;
    zz = xcd >> 1;
    m0 = ((xcd & 1) * 16 + (s >> 3)) * 128;
    n0 = (s & 7) * 128;
    k0 = zz * Klen;
  } else {
    n0 = blockIdx.x * 128;
    m0 = blockIdx.y * 128;
  }
  gemm_core<MODE>(As, Bs, threadIdx.x, m0, n0, k0, zz, A, B, ld, Klen, o0, o1,
                  o2, b0, b1, b2, fout, rowsum);
}

// Converts X|Wq|Wk|Wv to bf16; last 16 blocks zero rowsum (4096 f32).
__global__ __launch_bounds__(256) void cvt_all(
    const float* __restrict__ X, const float* __restrict__ Wq,
    const float* __restrict__ Wk, const float* __restrict__ Wv,
    bf16_t* __restrict__ Xb, bf16_t* __restrict__ Wb,
    float* __restrict__ rowsum) {
  int i = blockIdx.x * 256 + threadIdx.x;
  if (i >= 1835008) {
    rowsum[i - 1835008] = 0.f;
    return;
  }
  const float* src;
  bf16_t* dst;
  int off;
  if (i < 1048576) {
    src = X; dst = Xb; off = i;
  } else {
    const int w = i - 1048576;
    const int sel = w >> 18;
    off = w & 0x3FFFF;
    src = (sel == 0) ? Wq : ((sel == 1) ? Wk : Wv);
    dst = Wb + (size_t)sel * (1024 * 1024);
  }
  const float4 v = ((const float4*)src)[off];
  bf16x4 o;
  o[0] = (bf16_t)v.x; o[1] = (bf16_t)v.y; o[2] = (bf16_t)v.z; o[3] = (bf16_t)v.w;
  ((bf16x4*)dst)[off] = o;
}

// out[i] += f32(p0[i]) + f32(p1[i]) + f32(p2[i]);  8 elems/thread.
__global__ __launch_bounds__(256) void reduce_out(
    const bf16_t* __restrict__ p0, const bf16_t* __restrict__ p1,
    const bf16_t* __restrict__ p2, float* __restrict__ out) {
  const int i = blockIdx.x * 256 + threadIdx.x;
  const bf16x8 a = ((const bf16x8*)p0)[i];
  const bf16x8 b = ((const bf16x8*)p1)[i];
  const bf16x8 c = ((const bf16x8*)p2)[i];
  float4 lo = ((const float4*)out)[2 * i];
  float4 hi = ((const float4*)out)[2 * i + 1];
  lo.x += (float)a[0] + (float)b[0] + (float)c[0];
  lo.y += (float)a[1] + (float)b[1] + (float)c[1];
  lo.z += (float)a[2] + (float)b[2] + (float)c[2];
  lo.w += (float)a[3] + (float)b[3] + (float)c[3];
  hi.x += (float)a[4] + (float)b[4] + (float)c[4];
  hi.y += (float)a[5] + (float)b[5] + (float)c[5];
  hi.z += (float)a[6] + (float)b[6] + (float)c[6];
  hi.w += (float)a[7] + (float)b[7] + (float)c[7];
  ((float4*)out)[2 * i] = lo;
  ((float4*)out)[2 * i + 1] = hi;
}

extern "C" void kernel_launch(void* const* d_in, const int* in_sizes, int n_in,
                              void* d_out, int out_size, void* d_ws,
                              size_t ws_size, hipStream_t stream) {
  const int S = 4096, D = 1024;
  const float* X  = (const float*)d_in[0];
  const float* Wq = (const float*)d_in[1];
  const float* bq = (const float*)d_in[2];
  const float* Wk = (const float*)d_in[3];
  const float* bk = (const float*)d_in[4];
  const float* Wv = (const float*)d_in[5];
  const float* bv = (const float*)d_in[6];
  float* out = (float*)d_out;

  // ws layout (70 MB bf16 + 16 KB fp32). G3 split-K=4 partials reuse dead
  // regions: Xb (dead after G1), Qb, Kb (dead after G2); z=3 goes to d_out.
  bf16_t* Xb = (bf16_t*)d_ws;            // [4096][1024]
  bf16_t* Wb = Xb + (size_t)S * D;       // [3072][1024]
  bf16_t* Qb = Wb + (size_t)3 * D * D;   // [4096][1024], pre-scaled by 1/32
  bf16_t* Kb = Qb + (size_t)S * D;       // [4096][1024]
  bf16_t* Vt = Kb + (size_t)S * D;       // [1024][4096]  V transposed
  bf16_t* Sc = Vt + (size_t)D * S;       // [4096][4096]  exp(scores)
  float* rowsum = (float*)(Sc + (size_t)S * S);  // [4096]

  cvt_all<<<7184, 256, 0, stream>>>(X, Wq, Wk, Wv, Xb, Wb, rowsum);

  // G1: QKV = Xb @ Wb^T + bias  (M=4096, N=3072, K=1024), grid 768 (3/CU)
  gemm_sep<0><<<dim3(24, 32), 256, 0, stream>>>(
      Xb, Wb, D, D, Qb, Kb, Vt, bq, bk, bv, nullptr, nullptr);
  // G2: Sc = exp(Qb @ Kb^T), rowsum partials  (M=N=4096, K=1024), grid 1024
  gemm_sep<1><<<dim3(32, 32), 256, 0, stream>>>(
      Qb, Kb, D, D, Sc, nullptr, nullptr, nullptr, nullptr, nullptr, nullptr,
      rowsum);
  // G3: O-partials = (Sc @ Vt^T)/rowsum, K split 4x1024, grid 1024, XCD decode
  gemm_sep<2><<<1024, 256, 0, stream>>>(
      Sc, Vt, S, S / 4, Xb, Qb, Kb, nullptr, nullptr, nullptr, out, rowsum);
  // out += p0 + p1 + p2
  reduce_out<<<S * D / 8 / 256, 256, 0, stream>>>(Xb, Qb, Kb, out);
}